// Round 1
// baseline (30152.994 us; speedup 1.0000x reference)
//
#include <hip/hip_runtime.h>
#include <math.h>

#define D_DIM 256
#define KSEL  16
#define BQ    64
#define BN    64
#define DK    32
#define CHUNK 1600
#define NTILES (CHUNK / BN)   // 25
#define LDP   (BQ + 4)        // padded LDS stride (68) — 16B aligned, conflict-light

__device__ __forceinline__ bool pair_less(float a, int ia, float b, int ib) {
    return (a < b) || (a == b && ia < ib);
}

// Branchless sorted insert into bd[0..15]/bi[0..15] (ascending). All indices
// compile-time (rule #20: runtime-indexed register arrays spill to scratch).
#define INSERT_CAND(sval, ival)                                              \
    do {                                                                     \
        _Pragma("unroll")                                                    \
        for (int jj = KSEL - 1; jj >= 1; --jj) {                             \
            bool cj  = pair_less((sval), (ival), bd[jj], bi[jj]);            \
            bool cj1 = pair_less((sval), (ival), bd[jj - 1], bi[jj - 1]);    \
            bd[jj] = cj ? (cj1 ? bd[jj - 1] : (sval)) : bd[jj];              \
            bi[jj] = cj ? (cj1 ? bi[jj - 1] : (ival)) : bi[jj];              \
        }                                                                    \
        if (pair_less((sval), (ival), bd[0], bi[0])) {                       \
            bd[0] = (sval); bi[0] = (ival);                                  \
        }                                                                    \
    } while (0)

// ---------------------------------------------------------------- y2 norms
__global__ __launch_bounds__(256) void knn_y2(const float* __restrict__ y,
                                              float* __restrict__ y2, int N) {
    int gw   = (blockIdx.x * 256 + threadIdx.x) >> 6;  // one wave per row
    int lane = threadIdx.x & 63;
    if (gw >= N) return;
    const float4 v =
        *reinterpret_cast<const float4*>(y + (size_t)gw * D_DIM + lane * 4);
    float s = v.x * v.x + v.y * v.y + v.z * v.z + v.w * v.w;
#pragma unroll
    for (int off = 32; off > 0; off >>= 1) s += __shfl_down(s, off, 64);
    if (lane == 0) y2[gw] = s;
}

// ------------------------------------------- fused GEMM + per-chunk top-16
__global__ __launch_bounds__(256, 4) void knn_phase1(
    const float* __restrict__ x, const float* __restrict__ y,
    const float* __restrict__ y2, float* __restrict__ pd,
    int* __restrict__ pi, int N, int S) {
    __shared__ float xs[DK][LDP];      // transposed: xs[d][q]
    __shared__ float ys[DK][LDP];      // transposed: ys[d][n]
    __shared__ float sc[BQ][BN + 4];   // score tile, padded

    const int tid   = threadIdx.x;
    const int qbase = blockIdx.x * BQ;
    const int chunk = blockIdx.y;
    const int tq    = tid >> 4;        // 0..15 -> q micro-row
    const int tn    = tid & 15;        // 0..15 -> n micro-col

    float bd[KSEL];
    int   bi[KSEL];
#pragma unroll
    for (int j = 0; j < KSEL; ++j) { bd[j] = __builtin_inff(); bi[j] = 0x7fffffff; }

    const int sr = tid >> 3;           // staging row 0..31
    const int scol = (tid & 7) * 4;    // staging col 0,4,...,28

    for (int t = 0; t < NTILES; ++t) {
        const int nbase = chunk * CHUNK + t * BN;

        float acc[4][4];
#pragma unroll
        for (int i = 0; i < 4; ++i)
#pragma unroll
            for (int j = 0; j < 4; ++j) acc[i][j] = 0.0f;

        for (int dk = 0; dk < D_DIM; dk += DK) {
            __syncthreads();
            // stage x-tile and y-tile, transposed into LDS
#pragma unroll
            for (int h = 0; h < 2; ++h) {
                const int rr = sr + h * 32;
                const float4 xv = *reinterpret_cast<const float4*>(
                    x + (size_t)(qbase + rr) * D_DIM + dk + scol);
                xs[scol + 0][rr] = xv.x;
                xs[scol + 1][rr] = xv.y;
                xs[scol + 2][rr] = xv.z;
                xs[scol + 3][rr] = xv.w;

                const int yr = nbase + rr;
                float4 yv = make_float4(0.f, 0.f, 0.f, 0.f);
                if (yr < N)
                    yv = *reinterpret_cast<const float4*>(
                        y + (size_t)yr * D_DIM + dk + scol);
                ys[scol + 0][rr] = yv.x;
                ys[scol + 1][rr] = yv.y;
                ys[scol + 2][rr] = yv.z;
                ys[scol + 3][rr] = yv.w;
            }
            __syncthreads();

#pragma unroll
            for (int d = 0; d < DK; ++d) {
                const float4 xa =
                    *reinterpret_cast<const float4*>(&xs[d][tq * 4]);
                const float4 yb =
                    *reinterpret_cast<const float4*>(&ys[d][tn * 4]);
                acc[0][0] = fmaf(xa.x, yb.x, acc[0][0]);
                acc[0][1] = fmaf(xa.x, yb.y, acc[0][1]);
                acc[0][2] = fmaf(xa.x, yb.z, acc[0][2]);
                acc[0][3] = fmaf(xa.x, yb.w, acc[0][3]);
                acc[1][0] = fmaf(xa.y, yb.x, acc[1][0]);
                acc[1][1] = fmaf(xa.y, yb.y, acc[1][1]);
                acc[1][2] = fmaf(xa.y, yb.z, acc[1][2]);
                acc[1][3] = fmaf(xa.y, yb.w, acc[1][3]);
                acc[2][0] = fmaf(xa.z, yb.x, acc[2][0]);
                acc[2][1] = fmaf(xa.z, yb.y, acc[2][1]);
                acc[2][2] = fmaf(xa.z, yb.z, acc[2][2]);
                acc[2][3] = fmaf(xa.z, yb.w, acc[2][3]);
                acc[3][0] = fmaf(xa.w, yb.x, acc[3][0]);
                acc[3][1] = fmaf(xa.w, yb.y, acc[3][1]);
                acc[3][2] = fmaf(xa.w, yb.z, acc[3][2]);
                acc[3][3] = fmaf(xa.w, yb.w, acc[3][3]);
            }
        }

        // score = ||y||^2 - 2*dot  (monotone with euclidean distance per query)
        float yv2[4];
#pragma unroll
        for (int j = 0; j < 4; ++j) {
            const int gn = nbase + tn * 4 + j;
            yv2[j] = (gn < N) ? y2[gn] : 0.0f;
        }
#pragma unroll
        for (int i = 0; i < 4; ++i) {
            const int qq = tq * 4 + i;
#pragma unroll
            for (int j = 0; j < 4; ++j) {
                const int gn = nbase + tn * 4 + j;
                sc[qq][tn * 4 + j] =
                    (gn < N) ? fmaf(-2.0f, acc[i][j], yv2[j]) : __builtin_inff();
            }
        }
        __syncthreads();

        // wave 0: one lane per query scans the 64 scores (rotated start ->
        // conflict-free: bank = (5*lane + j) % 32 is a bijection mod 32)
        if (tid < BQ) {
#pragma unroll 1
            for (int j0 = 0; j0 < BN; ++j0) {
                const int j  = (j0 + tid) & (BN - 1);
                const int gn = nbase + j;
                const float s = sc[tid][j];
                if (gn < N && pair_less(s, gn, bd[KSEL - 1], bi[KSEL - 1])) {
                    INSERT_CAND(s, gn);
                }
            }
        }
        __syncthreads();
    }

    if (tid < BQ) {
        const size_t base = ((size_t)(qbase + tid) * S + chunk) * KSEL;
#pragma unroll
        for (int j = 0; j < KSEL; ++j) {
            pd[base + j] = bd[j];
            pi[base + j] = bi[j];
        }
    }
}

// --------------------------------------------------- merge partial top-16s
__global__ __launch_bounds__(256) void knn_phase2(const float* __restrict__ pd,
                                                  const int* __restrict__ pi,
                                                  int* __restrict__ out, int S,
                                                  int Qtot) {
    const int q = blockIdx.x * 256 + threadIdx.x;
    if (q >= Qtot) return;

    float bd[KSEL];
    int   bi[KSEL];
#pragma unroll
    for (int j = 0; j < KSEL; ++j) { bd[j] = __builtin_inff(); bi[j] = 0x7fffffff; }

#pragma unroll 1
    for (int c = 0; c < S; ++c) {
        const float* pdl = pd + ((size_t)q * S + c) * KSEL;
        const int*   pil = pi + ((size_t)q * S + c) * KSEL;
#pragma unroll 1
        for (int j = 0; j < KSEL; ++j) {   // partial list is sorted: early exit
            const float v  = pdl[j];
            const int   id = pil[j];
            if (!pair_less(v, id, bd[KSEL - 1], bi[KSEL - 1])) break;
            INSERT_CAND(v, id);
        }
    }

#pragma unroll
    for (int j = 0; j < KSEL; ++j) out[q * KSEL + j] = bi[j];
}

extern "C" void kernel_launch(void* const* d_in, const int* in_sizes, int n_in,
                              void* d_out, int out_size, void* d_ws,
                              size_t ws_size, hipStream_t stream) {
    const float* x = (const float*)d_in[0];
    const float* y = (const float*)d_in[1];
    int* out = (int*)d_out;

    const int Q = in_sizes[0] / D_DIM;   // 2048
    const int N = in_sizes[1] / D_DIM;   // 100000
    const int S = (N + CHUNK - 1) / CHUNK;  // 63

    float* y2 = (float*)d_ws;
    float* pd = y2 + N;
    int*   pi = (int*)(pd + (size_t)Q * S * KSEL);

    knn_y2<<<(N * 64 + 255) / 256, 256, 0, stream>>>(y, y2, N);
    knn_phase1<<<dim3(Q / BQ, S), 256, 0, stream>>>(x, y, y2, pd, pi, N, S);
    knn_phase2<<<(Q + 255) / 256, 256, 0, stream>>>(pd, pi, out, S, Q);
}

// Round 2
// 4073.907 us; speedup vs baseline: 7.4015x; 7.4015x over previous
//
#include <hip/hip_runtime.h>
#include <math.h>

#define D_DIM 256
#define KSEL  16
#define BQ    64
#define BN    64
#define DK    32
#define CHUNK 1600
#define NTILES (CHUNK / BN)       // 25
#define LDP   68                  // padded stride, multiple of 4 (b128-aligned)

// shared-memory word offsets (floats). Tile phase: xs | ys | sc.
// Merge phase (after tile loop): md | mi reuse the same storage.
#define XS_OFF 0
#define YS_OFF (DK * LDP)                 // 2176
#define SC_OFF (2 * DK * LDP)             // 4352
#define SMEM_WORDS (SC_OFF + BQ * LDP)    // 8704 words = 34816 B
#define MD_OFF 0                          // float md[4][64][17] = 4352 words
#define MI_OFF 4352                       // int   mi[4][64][17] = 4352 words

__device__ __forceinline__ bool pair_less(float a, int ia, float b, int ib) {
    return (a < b) || (a == b && ia < ib);
}

// Branchless sorted insert into bd[0..15]/bi[0..15] (ascending). All indices
// compile-time (rule #20: runtime-indexed register arrays spill to scratch).
#define INSERT_CAND(sval, ival)                                              \
    do {                                                                     \
        _Pragma("unroll")                                                    \
        for (int jj = KSEL - 1; jj >= 1; --jj) {                             \
            bool cj  = pair_less((sval), (ival), bd[jj], bi[jj]);            \
            bool cj1 = pair_less((sval), (ival), bd[jj - 1], bi[jj - 1]);    \
            bd[jj] = cj ? (cj1 ? bd[jj - 1] : (sval)) : bd[jj];              \
            bi[jj] = cj ? (cj1 ? bi[jj - 1] : (ival)) : bi[jj];              \
        }                                                                    \
        if (pair_less((sval), (ival), bd[0], bi[0])) {                       \
            bd[0] = (sval); bi[0] = (ival);                                  \
        }                                                                    \
    } while (0)

// ---------------------------------------------------------------- y2 norms
__global__ __launch_bounds__(256) void knn_y2(const float* __restrict__ y,
                                              float* __restrict__ y2, int N) {
    int gw   = (blockIdx.x * 256 + threadIdx.x) >> 6;  // one wave per row
    int lane = threadIdx.x & 63;
    if (gw >= N) return;
    const float4 v =
        *reinterpret_cast<const float4*>(y + (size_t)gw * D_DIM + lane * 4);
    float s = v.x * v.x + v.y * v.y + v.z * v.z + v.w * v.w;
#pragma unroll
    for (int off = 32; off > 0; off >>= 1) s += __shfl_down(s, off, 64);
    if (lane == 0) y2[gw] = s;
}

// ------------------------------------------- fused GEMM + per-chunk top-16
// NOTE: no min-waves clamp — round 1's __launch_bounds__(256,4) forced a
// 64-VGPR tier and spilled bd/bi to scratch (1.3 GB HBM writes, 30 ms).
__global__ __launch_bounds__(256) void knn_phase1(
    const float* __restrict__ x, const float* __restrict__ y,
    const float* __restrict__ y2, float* __restrict__ pd,
    int* __restrict__ pi, int N, int S) {
    __shared__ float smem[SMEM_WORDS];

    const int tid   = threadIdx.x;
    const int qbase = blockIdx.x * BQ;
    const int chunk = blockIdx.y;
    const int tq    = tid >> 4;        // 0..15 -> q micro-row
    const int tn    = tid & 15;        // 0..15 -> n micro-col
    const int q     = tid & 63;        // scan: query row
    const int part  = tid >> 6;        // scan: which 16-col quarter

    float bd[KSEL];
    int   bi[KSEL];
#pragma unroll
    for (int j = 0; j < KSEL; ++j) { bd[j] = __builtin_inff(); bi[j] = 0x7fffffff; }

    const int sr   = tid >> 3;         // staging row 0..31
    const int scol = (tid & 7) * 4;    // staging col 0,4,...,28

    for (int t = 0; t < NTILES; ++t) {
        const int nbase = chunk * CHUNK + t * BN;

        float acc[4][4];
#pragma unroll
        for (int i = 0; i < 4; ++i)
#pragma unroll
            for (int j = 0; j < 4; ++j) acc[i][j] = 0.0f;

        for (int dk = 0; dk < D_DIM; dk += DK) {
            __syncthreads();
            // stage x-tile and y-tile, transposed into LDS (xs[d][q], ys[d][n])
#pragma unroll
            for (int h = 0; h < 2; ++h) {
                const int rr = sr + h * 32;
                const float4 xv = *reinterpret_cast<const float4*>(
                    x + (size_t)(qbase + rr) * D_DIM + dk + scol);
                smem[XS_OFF + (scol + 0) * LDP + rr] = xv.x;
                smem[XS_OFF + (scol + 1) * LDP + rr] = xv.y;
                smem[XS_OFF + (scol + 2) * LDP + rr] = xv.z;
                smem[XS_OFF + (scol + 3) * LDP + rr] = xv.w;

                const int yr = nbase + rr;
                float4 yv = make_float4(0.f, 0.f, 0.f, 0.f);
                if (yr < N)
                    yv = *reinterpret_cast<const float4*>(
                        y + (size_t)yr * D_DIM + dk + scol);
                smem[YS_OFF + (scol + 0) * LDP + rr] = yv.x;
                smem[YS_OFF + (scol + 1) * LDP + rr] = yv.y;
                smem[YS_OFF + (scol + 2) * LDP + rr] = yv.z;
                smem[YS_OFF + (scol + 3) * LDP + rr] = yv.w;
            }
            __syncthreads();

#pragma unroll
            for (int d = 0; d < DK; ++d) {
                const float4 xa = *reinterpret_cast<const float4*>(
                    &smem[XS_OFF + d * LDP + tq * 4]);
                const float4 yb = *reinterpret_cast<const float4*>(
                    &smem[YS_OFF + d * LDP + tn * 4]);
                acc[0][0] = fmaf(xa.x, yb.x, acc[0][0]);
                acc[0][1] = fmaf(xa.x, yb.y, acc[0][1]);
                acc[0][2] = fmaf(xa.x, yb.z, acc[0][2]);
                acc[0][3] = fmaf(xa.x, yb.w, acc[0][3]);
                acc[1][0] = fmaf(xa.y, yb.x, acc[1][0]);
                acc[1][1] = fmaf(xa.y, yb.y, acc[1][1]);
                acc[1][2] = fmaf(xa.y, yb.z, acc[1][2]);
                acc[1][3] = fmaf(xa.y, yb.w, acc[1][3]);
                acc[2][0] = fmaf(xa.z, yb.x, acc[2][0]);
                acc[2][1] = fmaf(xa.z, yb.y, acc[2][1]);
                acc[2][2] = fmaf(xa.z, yb.z, acc[2][2]);
                acc[2][3] = fmaf(xa.z, yb.w, acc[2][3]);
                acc[3][0] = fmaf(xa.w, yb.x, acc[3][0]);
                acc[3][1] = fmaf(xa.w, yb.y, acc[3][1]);
                acc[3][2] = fmaf(xa.w, yb.z, acc[3][2]);
                acc[3][3] = fmaf(xa.w, yb.w, acc[3][3]);
            }
        }

        // score = ||y||^2 - 2*dot (monotone with euclidean distance per query).
        // float4 writes, stride 68: 8 disjoint 4-bank groups -> ~conflict-free.
        float yv2[4];
#pragma unroll
        for (int j = 0; j < 4; ++j) {
            const int gn = nbase + tn * 4 + j;
            yv2[j] = (gn < N) ? y2[gn] : 0.0f;
        }
#pragma unroll
        for (int i = 0; i < 4; ++i) {
            const int qq = tq * 4 + i;
            float4 sv;
            sv.x = (nbase + tn * 4 + 0 < N) ? fmaf(-2.0f, acc[i][0], yv2[0])
                                            : __builtin_inff();
            sv.y = (nbase + tn * 4 + 1 < N) ? fmaf(-2.0f, acc[i][1], yv2[1])
                                            : __builtin_inff();
            sv.z = (nbase + tn * 4 + 2 < N) ? fmaf(-2.0f, acc[i][2], yv2[2])
                                            : __builtin_inff();
            sv.w = (nbase + tn * 4 + 3 < N) ? fmaf(-2.0f, acc[i][3], yv2[3])
                                            : __builtin_inff();
            *reinterpret_cast<float4*>(&smem[SC_OFF + qq * LDP + tn * 4]) = sv;
        }
        __syncthreads();

        // parallel scan: ALL 256 threads. thread -> (query q, 16-col quarter).
        // rotated start spreads banks; each thread keeps its own top-16.
        {
            const float* scrow = &smem[SC_OFF + q * LDP + part * 16];
#pragma unroll 1
            for (int j0 = 0; j0 < 16; ++j0) {
                const int jc = (j0 + q) & 15;
                const int gn = nbase + part * 16 + jc;
                const float s = scrow[jc];
                if (gn < N && pair_less(s, gn, bd[KSEL - 1], bi[KSEL - 1])) {
                    INSERT_CAND(s, gn);
                }
            }
        }
        __syncthreads();
    }

    // ---- in-block merge: 4 quarter-lists -> 1 list per query (reuses smem)
    {
        float* md = &smem[MD_OFF];
        int*   mi = (int*)&smem[MI_OFF];
#pragma unroll
        for (int j = 0; j < KSEL; ++j) {
            md[(part * BQ + q) * 17 + j] = bd[j];
            mi[(part * BQ + q) * 17 + j] = bi[j];
        }
        __syncthreads();
        if (tid < BQ) {  // thread tid owns query tid; its regs hold part-0 list
#pragma unroll 1
            for (int p = 1; p < 4; ++p) {
#pragma unroll 1
                for (int j = 0; j < KSEL; ++j) {
                    const float v  = md[(p * BQ + tid) * 17 + j];
                    const int   id = mi[(p * BQ + tid) * 17 + j];
                    if (!pair_less(v, id, bd[KSEL - 1], bi[KSEL - 1])) break;
                    INSERT_CAND(v, id);
                }
            }
            const size_t base = ((size_t)(qbase + tid) * S + chunk) * KSEL;
#pragma unroll
            for (int j = 0; j < KSEL; ++j) {
                pd[base + j] = bd[j];
                pi[base + j] = bi[j];
            }
        }
    }
}

// --------------------------------------------------- merge partial top-16s
__global__ __launch_bounds__(256) void knn_phase2(const float* __restrict__ pd,
                                                  const int* __restrict__ pi,
                                                  int* __restrict__ out, int S,
                                                  int Qtot) {
    const int q = blockIdx.x * 256 + threadIdx.x;
    if (q >= Qtot) return;

    float bd[KSEL];
    int   bi[KSEL];
#pragma unroll
    for (int j = 0; j < KSEL; ++j) { bd[j] = __builtin_inff(); bi[j] = 0x7fffffff; }

#pragma unroll 1
    for (int c = 0; c < S; ++c) {
        const float* pdl = pd + ((size_t)q * S + c) * KSEL;
        const int*   pil = pi + ((size_t)q * S + c) * KSEL;
#pragma unroll 1
        for (int j = 0; j < KSEL; ++j) {   // partial list is sorted: early exit
            const float v  = pdl[j];
            const int   id = pil[j];
            if (!pair_less(v, id, bd[KSEL - 1], bi[KSEL - 1])) break;
            INSERT_CAND(v, id);
        }
    }

#pragma unroll
    for (int j = 0; j < KSEL; ++j) out[q * KSEL + j] = bi[j];
}

extern "C" void kernel_launch(void* const* d_in, const int* in_sizes, int n_in,
                              void* d_out, int out_size, void* d_ws,
                              size_t ws_size, hipStream_t stream) {
    const float* x = (const float*)d_in[0];
    const float* y = (const float*)d_in[1];
    int* out = (int*)d_out;

    const int Q = in_sizes[0] / D_DIM;      // 2048
    const int N = in_sizes[1] / D_DIM;      // 100000
    const int S = (N + CHUNK - 1) / CHUNK;  // 63

    float* y2 = (float*)d_ws;
    float* pd = y2 + N;
    int*   pi = (int*)(pd + (size_t)Q * S * KSEL);

    knn_y2<<<(N * 64 + 255) / 256, 256, 0, stream>>>(y, y2, N);
    knn_phase1<<<dim3(Q / BQ, S), 256, 0, stream>>>(x, y, y2, pd, pi, N, S);
    knn_phase2<<<(Q + 255) / 256, 256, 0, stream>>>(pd, pi, out, S, Q);
}